// Round 1
// baseline (1310.995 us; speedup 1.0000x reference)
//
#include <hip/hip_runtime.h>
#include <hip/hip_bf16.h>
#include <stdint.h>

typedef __hip_bfloat16 bf16_t;
typedef __attribute__((ext_vector_type(8))) short bf16x8;   // 8 bf16 = 4 VGPR
typedef __attribute__((ext_vector_type(4))) float f32x4;

#define DEV static __device__ __forceinline__

constexpr int kBB = 8, kL = 2048, kD = 1024;
constexpr int kM = kBB * kL;   // 16384 rows

DEV float bf2f(unsigned short u) { return __uint_as_float((unsigned)u << 16); }
DEV unsigned short f2bf(float f) {
  unsigned u = __float_as_uint(f);
  return (unsigned short)((u + 0x7fffu + ((u >> 16) & 1u)) >> 16);  // RNE
}

// async global->LDS, 16B per lane. LDS dest is wave-uniform-base + lane*16.
DEV void gld16(const void* g, void* l) {
  const __attribute__((address_space(1))) unsigned* gp =
      (const __attribute__((address_space(1))) unsigned*)(uintptr_t)g;
  __attribute__((address_space(3))) unsigned* lp =
      (__attribute__((address_space(3))) unsigned*)(unsigned)(uintptr_t)l;
  __builtin_amdgcn_global_load_lds(gp, lp, 16, 0, 0);
}

// ---------------- weight transpose + cast: W[R][C] f32 -> Wt[C][R] bf16 ---------------
__global__ __launch_bounds__(256) void k_transpose_cast(
    const float* __restrict__ W, bf16_t* __restrict__ Wt, int R, int C) {
  __shared__ float tile[32][33];
  const int bx = blockIdx.x * 32;           // C-dim base
  const int by = blockIdx.y * 32;           // R-dim base
  const int tx = threadIdx.x & 31, ty = threadIdx.x >> 5;  // 32 x 8
#pragma unroll
  for (int i = 0; i < 32; i += 8)
    tile[ty + i][tx] = W[(size_t)(by + ty + i) * C + (bx + tx)];
  __syncthreads();
#pragma unroll
  for (int i = 0; i < 32; i += 8)
    Wt[(size_t)(bx + ty + i) * R + (by + tx)] = __float2bfloat16(tile[tx][ty + i]);
}

// ---------------- LayerNorm row stats: one wave per row ----------------
__global__ __launch_bounds__(256) void k_ln_stats(
    const float* __restrict__ X, float* __restrict__ mean, float* __restrict__ rstd) {
  const int row = blockIdx.x * 4 + (threadIdx.x >> 6);
  const int lane = threadIdx.x & 63;
  const float4* xr = (const float4*)(X + (size_t)row * kD);
  float s = 0.f, s2 = 0.f;
#pragma unroll
  for (int i = 0; i < 4; ++i) {
    float4 v = xr[lane + 64 * i];
    s += v.x + v.y + v.z + v.w;
    s2 += v.x * v.x + v.y * v.y + v.z * v.z + v.w * v.w;
  }
#pragma unroll
  for (int off = 32; off > 0; off >>= 1) {
    s += __shfl_xor(s, off);
    s2 += __shfl_xor(s2, off);
  }
  if (lane == 0) {
    float m = s * (1.f / kD);
    float var = fmaxf(s2 * (1.f / kD) - m * m, 0.f);   // biased var
    mean[row] = m;
    rstd[row] = rsqrtf(var + 1e-5f);
  }
}

// ---------------- LN apply + shift + time-mix -> xk/xv/xr (bf16) ----------------
__global__ __launch_bounds__(256) void k_ln_mix1(
    const float* __restrict__ X, const float* __restrict__ mean, const float* __restrict__ rstd,
    const float* __restrict__ g, const float* __restrict__ be,
    const float* __restrict__ mk, const float* __restrict__ mv, const float* __restrict__ mr,
    bf16_t* __restrict__ ok, bf16_t* __restrict__ ov, bf16_t* __restrict__ orr) {
  const int row = blockIdx.x;
  const int l = row & (kL - 1);
  const int i = threadIdx.x;                 // 4 floats per thread
  const bool hp = (l != 0);
  const float m0 = mean[row], s0 = rstd[row];
  const float m1 = hp ? mean[row - 1] : 0.f;
  const float s1 = hp ? rstd[row - 1] : 0.f;
  float xa[4], pa[4] = {0.f, 0.f, 0.f, 0.f}, ga[4], ba[4], ka[4], va[4], ra[4];
  *(float4*)xa = ((const float4*)(X + (size_t)row * kD))[i];
  if (hp) *(float4*)pa = ((const float4*)(X + (size_t)(row - 1) * kD))[i];
  *(float4*)ga = ((const float4*)g)[i];
  *(float4*)ba = ((const float4*)be)[i];
  *(float4*)ka = ((const float4*)mk)[i];
  *(float4*)va = ((const float4*)mv)[i];
  *(float4*)ra = ((const float4*)mr)[i];
  ushort4 uk, uv, ur;
  unsigned short* pk = (unsigned short*)&uk;
  unsigned short* pv = (unsigned short*)&uv;
  unsigned short* pr = (unsigned short*)&ur;
#pragma unroll
  for (int c = 0; c < 4; ++c) {
    float xn = (xa[c] - m0) * s0 * ga[c] + ba[c];
    float xp = hp ? (pa[c] - m1) * s1 * ga[c] + ba[c] : 0.f;   // shift: row 0 -> zeros
    pk[c] = f2bf(xn * ka[c] + xp * (1.f - ka[c]));
    pv[c] = f2bf(xn * va[c] + xp * (1.f - va[c]));
    pr[c] = f2bf(xn * ra[c] + xp * (1.f - ra[c]));
  }
  ((ushort4*)(ok + (size_t)row * kD))[i] = uk;
  ((ushort4*)(ov + (size_t)row * kD))[i] = uv;
  ((ushort4*)(orr + (size_t)row * kD))[i] = ur;
}

// ---------------- LN apply + shift for channel mix: ymix = 0.5(yn+yp), yn ----------------
__global__ __launch_bounds__(256) void k_ln_mix2(
    const float* __restrict__ X, const float* __restrict__ mean, const float* __restrict__ rstd,
    const float* __restrict__ g, const float* __restrict__ be,
    bf16_t* __restrict__ om, bf16_t* __restrict__ on) {
  const int row = blockIdx.x;
  const int l = row & (kL - 1);
  const int i = threadIdx.x;
  const bool hp = (l != 0);
  const float m0 = mean[row], s0 = rstd[row];
  const float m1 = hp ? mean[row - 1] : 0.f;
  const float s1 = hp ? rstd[row - 1] : 0.f;
  float xa[4], pa[4] = {0.f, 0.f, 0.f, 0.f}, ga[4], ba[4];
  *(float4*)xa = ((const float4*)(X + (size_t)row * kD))[i];
  if (hp) *(float4*)pa = ((const float4*)(X + (size_t)(row - 1) * kD))[i];
  *(float4*)ga = ((const float4*)g)[i];
  *(float4*)ba = ((const float4*)be)[i];
  ushort4 um, un;
  unsigned short* qm = (unsigned short*)&um;
  unsigned short* qn = (unsigned short*)&un;
#pragma unroll
  for (int c = 0; c < 4; ++c) {
    float yn = (xa[c] - m0) * s0 * ga[c] + ba[c];
    float yp = hp ? (pa[c] - m1) * s1 * ga[c] + ba[c] : 0.f;
    qm[c] = f2bf(0.5f * (yn + yp));
    qn[c] = f2bf(yn);
  }
  ((ushort4*)(om + (size_t)row * kD))[i] = um;
  ((ushort4*)(on + (size_t)row * kD))[i] = un;
}

// ---------------- WKV sequential scan, thread per (b,d), 16-step dbuf prefetch -------------
__global__ __launch_bounds__(256) void k_wkv(
    const unsigned short* __restrict__ kq, const unsigned short* __restrict__ vq,
    const unsigned short* __restrict__ rq, const float* __restrict__ td,
    const float* __restrict__ tf, unsigned short* __restrict__ out) {
  const int d = blockIdx.x * 256 + threadIdx.x;
  const int b = blockIdx.y;
  const float ew = __expf(-__expf(td[d]));
  const float uu = tf[d];
  const size_t base = (size_t)b * kL * kD + d;
  float a = 0.f, bb = 0.f;
  unsigned short kA[16], vA[16], rA[16], kB[16], vB[16], rB[16];
  auto pref = [&](unsigned short* ka, unsigned short* va, unsigned short* ra, int c) {
    const size_t o0 = base + (size_t)c * 16 * kD;
#pragma unroll
    for (int j = 0; j < 16; ++j) {
      ka[j] = kq[o0 + (size_t)j * kD];
      va[j] = vq[o0 + (size_t)j * kD];
      ra[j] = rq[o0 + (size_t)j * kD];
    }
  };
  auto comp = [&](const unsigned short* ka, const unsigned short* va,
                  const unsigned short* ra, int c) {
    const size_t o0 = base + (size_t)c * 16 * kD;
#pragma unroll
    for (int j = 0; j < 16; ++j) {
      float kf = bf2f(ka[j]);
      if (c == 0 && j == 0) kf += uu;          // t==0: e0 = exp(u + k0)
      float ek = __expf(kf);
      a = ew * a + ek * bf2f(va[j]);
      bb = ew * bb + ek;
      float y = a / (bb + 1e-8f);
      float sr = 1.f / (1.f + __expf(-bf2f(ra[j])));
      out[o0 + (size_t)j * kD] = f2bf(sr * y);
    }
  };
  pref(kA, vA, rA, 0);
  for (int c = 0; c < 128; c += 2) {           // 128 chunks x 16 = 2048 steps
    pref(kB, vB, rB, c + 1);
    comp(kA, vA, rA, c);
    if (c + 2 < 128) pref(kA, vA, rA, c + 2);
    comp(kB, vB, rB, c + 1);
  }
}

// ---------------- 128x128-tile bf16 MFMA GEMM, B^T input, fused epilogues ----------------
// EPI: 0=store bf16, 1=f32 addf+acc, 2=bf16 relu(acc)^2, 3=bf16 sigmoid(acc),
//      4=f32 store acc, 5=f32 Cf+=acc, 6=f32 addf + mulb*(Cf+acc)  [final combine]
template <int EPI>
__global__ __launch_bounds__(256) void gemm128(
    const bf16_t* __restrict__ A, int lda,        // A [M][lda], uses cols 0..K-1
    const bf16_t* __restrict__ Bt, int ldb,       // B^T [N][ldb], uses cols 0..K-1
    int N, int K,
    float* __restrict__ Cf, bf16_t* __restrict__ Cb,
    const float* __restrict__ addf, const bf16_t* __restrict__ mulb) {
  __shared__ bf16_t As[128 * 32];
  __shared__ bf16_t Bs[128 * 32];
  const int tid = threadIdx.x;
  const int lane = tid & 63;
  const int wid = tid >> 6;
  const int wr = wid >> 1, wc = wid & 1;          // 2x2 waves, 64x64 out each
  const long brow = (long)blockIdx.y * 128;
  const long bcol = (long)blockIdx.x * 128;

  f32x4 acc[4][4] = {};

  const int srow = tid >> 2;                      // staging row 0..63
  const int scolb = (tid & 3) * 16;               // byte col in 64B row
  const char* Ag = (const char*)(A + (brow + srow) * (size_t)lda) + scolb;
  const char* Bg = (const char*)(Bt + (bcol + srow) * (size_t)ldb) + scolb;
  const long rsa = 64L * lda * 2;
  const long rsb = 64L * ldb * 2;
  char* Al = (char*)As + tid * 16;
  char* Bl = (char*)Bs + tid * 16;

  const int l16 = lane & 15;
  const int kq = lane >> 4;
  const char* Afrag = (const char*)As + (wr * 64 + l16) * 64 + kq * 16;
  const char* Bfrag = (const char*)Bs + (wc * 64 + l16) * 64 + kq * 16;

  for (int kt = 0; kt < K; kt += 32) {
    __syncthreads();                              // LDS safe to overwrite
    gld16(Ag, Al);          gld16(Ag + rsa, Al + 4096);
    gld16(Bg, Bl);          gld16(Bg + rsb, Bl + 4096);
    Ag += 64; Bg += 64;
    asm volatile("s_waitcnt vmcnt(0)" ::: "memory");
    __syncthreads();
    bf16x8 af[4], bf[4];
#pragma unroll
    for (int m = 0; m < 4; ++m) af[m] = *(const bf16x8*)(Afrag + m * 16 * 64);
#pragma unroll
    for (int n = 0; n < 4; ++n) bf[n] = *(const bf16x8*)(Bfrag + n * 16 * 64);
#pragma unroll
    for (int m = 0; m < 4; ++m)
#pragma unroll
      for (int n = 0; n < 4; ++n)
        acc[m][n] = __builtin_amdgcn_mfma_f32_16x16x32_bf16(af[m], bf[n], acc[m][n], 0, 0, 0);
  }

  const long orow = brow + wr * 64 + (lane >> 4) * 4;   // C/D: col=lane&15, row=(lane>>4)*4+reg
  const long ocol = bcol + wc * 64 + l16;
#pragma unroll
  for (int m = 0; m < 4; ++m) {
#pragma unroll
    for (int reg = 0; reg < 4; ++reg) {
      const long r = orow + m * 16 + reg;
#pragma unroll
      for (int n = 0; n < 4; ++n) {
        const size_t idx = (size_t)r * N + ocol + n * 16;
        const float v = acc[m][n][reg];
        if constexpr (EPI == 0) {
          Cb[idx] = __float2bfloat16(v);
        } else if constexpr (EPI == 1) {
          Cf[idx] = addf[idx] + v;
        } else if constexpr (EPI == 2) {
          float t = v > 0.f ? v : 0.f;
          Cb[idx] = __float2bfloat16(t * t);
        } else if constexpr (EPI == 3) {
          Cb[idx] = __float2bfloat16(1.f / (1.f + __expf(-v)));
        } else if constexpr (EPI == 4) {
          Cf[idx] = v;
        } else if constexpr (EPI == 5) {
          Cf[idx] += v;
        } else {
          Cf[idx] = addf[idx] + __bfloat162float(mulb[idx]) * (Cf[idx] + v);
        }
      }
    }
  }
}

extern "C" void kernel_launch(void* const* d_in, const int* in_sizes, int n_in,
                              void* d_out, int out_size, void* d_ws, size_t ws_size,
                              hipStream_t stream) {
  const float* x    = (const float*)d_in[0];
  const float* ln1g = (const float*)d_in[1];
  const float* ln1b = (const float*)d_in[2];
  const float* Wk   = (const float*)d_in[3];
  const float* Wv   = (const float*)d_in[4];
  const float* Wr   = (const float*)d_in[5];
  const float* Wo   = (const float*)d_in[6];
  const float* td   = (const float*)d_in[7];
  const float* tf   = (const float*)d_in[8];
  const float* mk   = (const float*)d_in[9];
  const float* mv   = (const float*)d_in[10];
  const float* mr   = (const float*)d_in[11];
  const float* ln2g = (const float*)d_in[12];
  const float* ln2b = (const float*)d_in[13];
  const float* Wfk  = (const float*)d_in[14];
  const float* Wfv  = (const float*)d_in[15];
  const float* Wfr  = (const float*)d_in[16];

  char* ws = (char*)d_ws;
  const size_t MB = 1ull << 20;
  // [0,26) weights bf16 (transposed), [26,27) LN stats; peak ws use = 220 MiB
  bf16_t* WkT  = (bf16_t*)(ws + 0 * MB);
  bf16_t* WvT  = (bf16_t*)(ws + 2 * MB);
  bf16_t* WrT  = (bf16_t*)(ws + 4 * MB);
  bf16_t* WoT  = (bf16_t*)(ws + 6 * MB);
  bf16_t* WfkT = (bf16_t*)(ws + 8 * MB);    // [4096][1024]
  bf16_t* WfvT = (bf16_t*)(ws + 16 * MB);   // [1024][4096]
  bf16_t* WfrT = (bf16_t*)(ws + 24 * MB);
  float* mean1 = (float*)(ws + 26 * MB);
  float* rstd1 = (float*)(ws + 26 * MB + 65536);
  float* mean2 = (float*)(ws + 26 * MB + 131072);
  float* rstd2 = (float*)(ws + 26 * MB + 196608);
  bf16_t* xk   = (bf16_t*)(ws + 28 * MB);   // later: rwkv, then kk-chunk
  bf16_t* xv   = (bf16_t*)(ws + 60 * MB);   // later: ymix
  bf16_t* xr   = (bf16_t*)(ws + 92 * MB);   // later: ynb
  bf16_t* kbuf = (bf16_t*)(ws + 124 * MB);  // later: x1 (f32, 124..188)
  bf16_t* vbuf = (bf16_t*)(ws + 156 * MB);
  bf16_t* rbuf = (bf16_t*)(ws + 188 * MB);  // later: rr
  bf16_t* rwkv = (bf16_t*)(ws + 28 * MB);
  float*  x1   = (float*)(ws + 124 * MB);
  bf16_t* ymix = (bf16_t*)(ws + 60 * MB);
  bf16_t* ynb  = (bf16_t*)(ws + 92 * MB);
  bf16_t* rr   = (bf16_t*)(ws + 188 * MB);
  bf16_t* kkc  = (bf16_t*)(ws + 28 * MB);
  float*  out  = (float*)d_out;

  dim3 blk(256);
  // weights -> bf16 B^T
  k_transpose_cast<<<dim3(32, 32), blk, 0, stream>>>(Wk, WkT, 1024, 1024);
  k_transpose_cast<<<dim3(32, 32), blk, 0, stream>>>(Wv, WvT, 1024, 1024);
  k_transpose_cast<<<dim3(32, 32), blk, 0, stream>>>(Wr, WrT, 1024, 1024);
  k_transpose_cast<<<dim3(32, 32), blk, 0, stream>>>(Wo, WoT, 1024, 1024);
  k_transpose_cast<<<dim3(128, 32), blk, 0, stream>>>(Wfk, WfkT, 1024, 4096);
  k_transpose_cast<<<dim3(32, 128), blk, 0, stream>>>(Wfv, WfvT, 4096, 1024);
  k_transpose_cast<<<dim3(32, 32), blk, 0, stream>>>(Wfr, WfrT, 1024, 1024);

  // time mixing
  k_ln_stats<<<kM / 4, blk, 0, stream>>>(x, mean1, rstd1);
  k_ln_mix1<<<kM, blk, 0, stream>>>(x, mean1, rstd1, ln1g, ln1b, mk, mv, mr, xk, xv, xr);
  gemm128<0><<<dim3(8, 128), blk, 0, stream>>>(xk, 1024, WkT, 1024, 1024, 1024, nullptr, kbuf, nullptr, nullptr);
  gemm128<0><<<dim3(8, 128), blk, 0, stream>>>(xv, 1024, WvT, 1024, 1024, 1024, nullptr, vbuf, nullptr, nullptr);
  gemm128<0><<<dim3(8, 128), blk, 0, stream>>>(xr, 1024, WrT, 1024, 1024, 1024, nullptr, rbuf, nullptr, nullptr);
  k_wkv<<<dim3(4, 8), blk, 0, stream>>>((const unsigned short*)kbuf, (const unsigned short*)vbuf,
                                        (const unsigned short*)rbuf, td, tf, (unsigned short*)rwkv);
  gemm128<1><<<dim3(8, 128), blk, 0, stream>>>(rwkv, 1024, WoT, 1024, 1024, 1024, x1, nullptr, x, nullptr);

  // channel mixing
  k_ln_stats<<<kM / 4, blk, 0, stream>>>(x1, mean2, rstd2);
  k_ln_mix2<<<kM, blk, 0, stream>>>(x1, mean2, rstd2, ln2g, ln2b, ymix, ynb);
  gemm128<3><<<dim3(8, 128), blk, 0, stream>>>(ynb, 1024, WfrT, 1024, 1024, 1024, nullptr, rr, nullptr, nullptr);
  // hidden dim chunked by 1024: kkc = relu(ymix@Wfk[:,c])^2 ; out (+)= kkc@Wfv[c,:]
  for (int c = 0; c < 4; ++c) {
    gemm128<2><<<dim3(8, 128), blk, 0, stream>>>(ymix, 1024, WfkT + (size_t)c * 1024 * 1024, 1024,
                                                 1024, 1024, nullptr, kkc, nullptr, nullptr);
    if (c == 0)
      gemm128<4><<<dim3(8, 128), blk, 0, stream>>>(kkc, 1024, WfvT + (size_t)c * 1024, 4096,
                                                   1024, 1024, out, nullptr, nullptr, nullptr);
    else if (c < 3)
      gemm128<5><<<dim3(8, 128), blk, 0, stream>>>(kkc, 1024, WfvT + (size_t)c * 1024, 4096,
                                                   1024, 1024, out, nullptr, nullptr, nullptr);
    else
      gemm128<6><<<dim3(8, 128), blk, 0, stream>>>(kkc, 1024, WfvT + (size_t)c * 1024, 4096,
                                                   1024, 1024, out, nullptr, x1, rr);
  }
}

// Round 2
// 1050.525 us; speedup vs baseline: 1.2479x; 1.2479x over previous
//
#include <hip/hip_runtime.h>
#include <hip/hip_bf16.h>
#include <stdint.h>

typedef __hip_bfloat16 bf16_t;
typedef __attribute__((ext_vector_type(8))) short bf16x8;   // 8 bf16 = 4 VGPR
typedef __attribute__((ext_vector_type(4))) float f32x4;

#define DEV static __device__ __forceinline__

constexpr int kBB = 8, kL = 2048, kD = 1024;
constexpr int kM = kBB * kL;   // 16384 rows
constexpr int kSeg = 32, kP = 64;   // WKV: 32 segments x 64 steps

DEV float bf2f(unsigned short u) { return __uint_as_float((unsigned)u << 16); }
DEV unsigned short f2bf(float f) {
  unsigned u = __float_as_uint(f);
  return (unsigned short)((u + 0x7fffu + ((u >> 16) & 1u)) >> 16);  // RNE
}

// async global->LDS, 16B per lane. LDS dest is wave-uniform-base + lane*16.
DEV void gld16(const void* g, void* l) {
  const __attribute__((address_space(1))) unsigned* gp =
      (const __attribute__((address_space(1))) unsigned*)(uintptr_t)g;
  __attribute__((address_space(3))) unsigned* lp =
      (__attribute__((address_space(3))) unsigned*)(unsigned)(uintptr_t)l;
  __builtin_amdgcn_global_load_lds(gp, lp, 16, 0, 0);
}

// ---------------- weight transpose + cast: W[R][C] f32 -> Wt[C][R] bf16 ---------------
__global__ __launch_bounds__(256) void k_transpose_cast(
    const float* __restrict__ W, bf16_t* __restrict__ Wt, int R, int C) {
  __shared__ float tile[32][33];
  const int bx = blockIdx.x * 32;           // C-dim base
  const int by = blockIdx.y * 32;           // R-dim base
  const int tx = threadIdx.x & 31, ty = threadIdx.x >> 5;  // 32 x 8
#pragma unroll
  for (int i = 0; i < 32; i += 8)
    tile[ty + i][tx] = W[(size_t)(by + ty + i) * C + (bx + tx)];
  __syncthreads();
#pragma unroll
  for (int i = 0; i < 32; i += 8)
    Wt[(size_t)(bx + ty + i) * R + (by + tx)] = __float2bfloat16(tile[tx][ty + i]);
}

// ---------------- LayerNorm row stats: one wave per row ----------------
__global__ __launch_bounds__(256) void k_ln_stats(
    const float* __restrict__ X, float* __restrict__ mean, float* __restrict__ rstd) {
  const int row = blockIdx.x * 4 + (threadIdx.x >> 6);
  const int lane = threadIdx.x & 63;
  const float4* xr = (const float4*)(X + (size_t)row * kD);
  float s = 0.f, s2 = 0.f;
#pragma unroll
  for (int i = 0; i < 4; ++i) {
    float4 v = xr[lane + 64 * i];
    s += v.x + v.y + v.z + v.w;
    s2 += v.x * v.x + v.y * v.y + v.z * v.z + v.w * v.w;
  }
#pragma unroll
  for (int off = 32; off > 0; off >>= 1) {
    s += __shfl_xor(s, off);
    s2 += __shfl_xor(s2, off);
  }
  if (lane == 0) {
    float m = s * (1.f / kD);
    float var = fmaxf(s2 * (1.f / kD) - m * m, 0.f);   // biased var
    mean[row] = m;
    rstd[row] = rsqrtf(var + 1e-5f);
  }
}

// ---------------- LN apply + shift + time-mix -> xk/xv/xr (bf16) ----------------
__global__ __launch_bounds__(256) void k_ln_mix1(
    const float* __restrict__ X, const float* __restrict__ mean, const float* __restrict__ rstd,
    const float* __restrict__ g, const float* __restrict__ be,
    const float* __restrict__ mk, const float* __restrict__ mv, const float* __restrict__ mr,
    bf16_t* __restrict__ ok, bf16_t* __restrict__ ov, bf16_t* __restrict__ orr) {
  const int row = blockIdx.x;
  const int l = row & (kL - 1);
  const int i = threadIdx.x;                 // 4 floats per thread
  const bool hp = (l != 0);
  const float m0 = mean[row], s0 = rstd[row];
  const float m1 = hp ? mean[row - 1] : 0.f;
  const float s1 = hp ? rstd[row - 1] : 0.f;
  float xa[4], pa[4] = {0.f, 0.f, 0.f, 0.f}, ga[4], ba[4], ka[4], va[4], ra[4];
  *(float4*)xa = ((const float4*)(X + (size_t)row * kD))[i];
  if (hp) *(float4*)pa = ((const float4*)(X + (size_t)(row - 1) * kD))[i];
  *(float4*)ga = ((const float4*)g)[i];
  *(float4*)ba = ((const float4*)be)[i];
  *(float4*)ka = ((const float4*)mk)[i];
  *(float4*)va = ((const float4*)mv)[i];
  *(float4*)ra = ((const float4*)mr)[i];
  ushort4 uk, uv, ur;
  unsigned short* pk = (unsigned short*)&uk;
  unsigned short* pv = (unsigned short*)&uv;
  unsigned short* pr = (unsigned short*)&ur;
#pragma unroll
  for (int c = 0; c < 4; ++c) {
    float xn = (xa[c] - m0) * s0 * ga[c] + ba[c];
    float xp = hp ? (pa[c] - m1) * s1 * ga[c] + ba[c] : 0.f;   // shift: row 0 -> zeros
    pk[c] = f2bf(xn * ka[c] + xp * (1.f - ka[c]));
    pv[c] = f2bf(xn * va[c] + xp * (1.f - va[c]));
    pr[c] = f2bf(xn * ra[c] + xp * (1.f - ra[c]));
  }
  ((ushort4*)(ok + (size_t)row * kD))[i] = uk;
  ((ushort4*)(ov + (size_t)row * kD))[i] = uv;
  ((ushort4*)(orr + (size_t)row * kD))[i] = ur;
}

// ---------------- LN apply + shift for channel mix: ymix = 0.5(yn+yp), yn ----------------
__global__ __launch_bounds__(256) void k_ln_mix2(
    const float* __restrict__ X, const float* __restrict__ mean, const float* __restrict__ rstd,
    const float* __restrict__ g, const float* __restrict__ be,
    bf16_t* __restrict__ om, bf16_t* __restrict__ on) {
  const int row = blockIdx.x;
  const int l = row & (kL - 1);
  const int i = threadIdx.x;
  const bool hp = (l != 0);
  const float m0 = mean[row], s0 = rstd[row];
  const float m1 = hp ? mean[row - 1] : 0.f;
  const float s1 = hp ? rstd[row - 1] : 0.f;
  float xa[4], pa[4] = {0.f, 0.f, 0.f, 0.f}, ga[4], ba[4];
  *(float4*)xa = ((const float4*)(X + (size_t)row * kD))[i];
  if (hp) *(float4*)pa = ((const float4*)(X + (size_t)(row - 1) * kD))[i];
  *(float4*)ga = ((const float4*)g)[i];
  *(float4*)ba = ((const float4*)be)[i];
  ushort4 um, un;
  unsigned short* qm = (unsigned short*)&um;
  unsigned short* qn = (unsigned short*)&un;
#pragma unroll
  for (int c = 0; c < 4; ++c) {
    float yn = (xa[c] - m0) * s0 * ga[c] + ba[c];
    float yp = hp ? (pa[c] - m1) * s1 * ga[c] + ba[c] : 0.f;
    qm[c] = f2bf(0.5f * (yn + yp));
    qn[c] = f2bf(yn);
  }
  ((ushort4*)(om + (size_t)row * kD))[i] = um;
  ((ushort4*)(on + (size_t)row * kD))[i] = un;
}

// ===================== WKV: segmented parallel scan over L =====================
// Linear recurrence a_t = ew*a_{t-1} + exp(k_t)*v_t with channel-constant ew.
// pass1: per (b,d,seg) local (A,B) from zero state. pass2: serial carry over
// 32 segments (ewP = ew^64). pass3: re-run segment from carry, emit sigmoid(r)*a/(b+eps).

__global__ __launch_bounds__(256) void k_wkv_seg(
    const unsigned short* __restrict__ kq, const unsigned short* __restrict__ vq,
    const float* __restrict__ td, const float* __restrict__ tf,
    float* __restrict__ segA, float* __restrict__ segB) {
  const int d = blockIdx.x * 256 + threadIdx.x;
  const int b = blockIdx.y;
  const int s = blockIdx.z;
  const float ew = __expf(-__expf(td[d]));
  const float uu = (s == 0) ? tf[d] : 0.f;
  const size_t base = ((size_t)b * kL + (size_t)s * kP) * kD + d;
  float a = 0.f, bb = 0.f;
  unsigned short kA[16], vA[16], kB[16], vB[16];
  auto pref = [&](unsigned short* ka, unsigned short* va, int c) {
    const size_t o0 = base + (size_t)c * 16 * kD;
#pragma unroll
    for (int j = 0; j < 16; ++j) {
      ka[j] = kq[o0 + (size_t)j * kD];
      va[j] = vq[o0 + (size_t)j * kD];
    }
  };
  auto comp = [&](const unsigned short* ka, const unsigned short* va, int c) {
#pragma unroll
    for (int j = 0; j < 16; ++j) {
      float kf = bf2f(ka[j]);
      if (s == 0 && c == 0 && j == 0) kf += uu;    // t==0: exp(u + k0)
      float ek = __expf(kf);
      a = ew * a + ek * bf2f(va[j]);
      bb = ew * bb + ek;
    }
  };
  pref(kA, vA, 0);
  pref(kB, vB, 1); comp(kA, vA, 0);
  pref(kA, vA, 2); comp(kB, vB, 1);
  pref(kB, vB, 3); comp(kA, vA, 2);
  comp(kB, vB, 3);
  const size_t sidx = ((size_t)b * kSeg + s) * kD + d;
  segA[sidx] = a;
  segB[sidx] = bb;
}

__global__ __launch_bounds__(256) void k_wkv_carry(
    const float* __restrict__ td,
    const float* __restrict__ segA, const float* __restrict__ segB,
    float* __restrict__ carA, float* __restrict__ carB) {
  const int d = blockIdx.x * 256 + threadIdx.x;
  const int b = blockIdx.y;
  const float ew = __expf(-__expf(td[d]));
  float ewP = ew;
#pragma unroll
  for (int i = 0; i < 6; ++i) ewP *= ewP;          // ew^64
  float ca = 0.f, cb = 0.f;
#pragma unroll 4
  for (int s = 0; s < kSeg; ++s) {
    const size_t idx = ((size_t)b * kSeg + s) * kD + d;
    carA[idx] = ca;
    carB[idx] = cb;
    ca = ewP * ca + segA[idx];
    cb = ewP * cb + segB[idx];
  }
}

__global__ __launch_bounds__(256) void k_wkv_out(
    const unsigned short* __restrict__ kq, const unsigned short* __restrict__ vq,
    const unsigned short* __restrict__ rq, const float* __restrict__ td,
    const float* __restrict__ tf, const float* __restrict__ carA,
    const float* __restrict__ carB, unsigned short* __restrict__ out) {
  const int d = blockIdx.x * 256 + threadIdx.x;
  const int b = blockIdx.y;
  const int s = blockIdx.z;
  const float ew = __expf(-__expf(td[d]));
  const float uu = (s == 0) ? tf[d] : 0.f;
  const size_t base = ((size_t)b * kL + (size_t)s * kP) * kD + d;
  const size_t sidx = ((size_t)b * kSeg + s) * kD + d;
  float a = carA[sidx], bb = carB[sidx];
  unsigned short kA[16], vA[16], rA[16], kB[16], vB[16], rB[16];
  auto pref = [&](unsigned short* ka, unsigned short* va, unsigned short* ra, int c) {
    const size_t o0 = base + (size_t)c * 16 * kD;
#pragma unroll
    for (int j = 0; j < 16; ++j) {
      ka[j] = kq[o0 + (size_t)j * kD];
      va[j] = vq[o0 + (size_t)j * kD];
      ra[j] = rq[o0 + (size_t)j * kD];
    }
  };
  auto comp = [&](const unsigned short* ka, const unsigned short* va,
                  const unsigned short* ra, int c) {
    const size_t o0 = base + (size_t)c * 16 * kD;
#pragma unroll
    for (int j = 0; j < 16; ++j) {
      float kf = bf2f(ka[j]);
      if (s == 0 && c == 0 && j == 0) kf += uu;
      float ek = __expf(kf);
      a = ew * a + ek * bf2f(va[j]);
      bb = ew * bb + ek;
      float y = a / (bb + 1e-8f);
      float sr = 1.f / (1.f + __expf(-bf2f(ra[j])));
      out[o0 + (size_t)j * kD] = f2bf(sr * y);
    }
  };
  pref(kA, vA, rA, 0);
  pref(kB, vB, rB, 1); comp(kA, vA, rA, 0);
  pref(kA, vA, rA, 2); comp(kB, vB, rB, 1);
  pref(kB, vB, rB, 3); comp(kA, vA, rA, 2);
  comp(kB, vB, rB, 3);
}

// ---------------- 128x128-tile bf16 MFMA GEMM, B^T input, fused epilogues ----------------
// EPI: 0=store bf16, 1=f32 addf+acc, 2=bf16 relu(acc)^2, 3=bf16 sigmoid(acc),
//      4=f32 store acc, 5=f32 Cf+=acc, 6=f32 addf + mulb*(Cf+acc)  [final combine]
template <int EPI>
__global__ __launch_bounds__(256) void gemm128(
    const bf16_t* __restrict__ A, int lda,        // A [M][lda], uses cols 0..K-1
    const bf16_t* __restrict__ Bt, int ldb,       // B^T [N][ldb], uses cols 0..K-1
    int N, int K,
    float* __restrict__ Cf, bf16_t* __restrict__ Cb,
    const float* __restrict__ addf, const bf16_t* __restrict__ mulb) {
  __shared__ bf16_t As[128 * 32];
  __shared__ bf16_t Bs[128 * 32];
  const int tid = threadIdx.x;
  const int lane = tid & 63;
  const int wid = tid >> 6;
  const int wr = wid >> 1, wc = wid & 1;          // 2x2 waves, 64x64 out each
  const long brow = (long)blockIdx.y * 128;
  const long bcol = (long)blockIdx.x * 128;

  f32x4 acc[4][4] = {};

  const int srow = tid >> 2;                      // staging row 0..63
  const int scolb = (tid & 3) * 16;               // byte col in 64B row
  const char* Ag = (const char*)(A + (brow + srow) * (size_t)lda) + scolb;
  const char* Bg = (const char*)(Bt + (bcol + srow) * (size_t)ldb) + scolb;
  const long rsa = 64L * lda * 2;
  const long rsb = 64L * ldb * 2;
  char* Al = (char*)As + tid * 16;
  char* Bl = (char*)Bs + tid * 16;

  const int l16 = lane & 15;
  const int kq = lane >> 4;
  const char* Afrag = (const char*)As + (wr * 64 + l16) * 64 + kq * 16;
  const char* Bfrag = (const char*)Bs + (wc * 64 + l16) * 64 + kq * 16;

  for (int kt = 0; kt < K; kt += 32) {
    __syncthreads();                              // LDS safe to overwrite
    gld16(Ag, Al);          gld16(Ag + rsa, Al + 4096);
    gld16(Bg, Bl);          gld16(Bg + rsb, Bl + 4096);
    Ag += 64; Bg += 64;
    asm volatile("s_waitcnt vmcnt(0)" ::: "memory");
    __syncthreads();
    bf16x8 af[4], bf[4];
#pragma unroll
    for (int m = 0; m < 4; ++m) af[m] = *(const bf16x8*)(Afrag + m * 16 * 64);
#pragma unroll
    for (int n = 0; n < 4; ++n) bf[n] = *(const bf16x8*)(Bfrag + n * 16 * 64);
#pragma unroll
    for (int m = 0; m < 4; ++m)
#pragma unroll
      for (int n = 0; n < 4; ++n)
        acc[m][n] = __builtin_amdgcn_mfma_f32_16x16x32_bf16(af[m], bf[n], acc[m][n], 0, 0, 0);
  }

  const long orow = brow + wr * 64 + (lane >> 4) * 4;   // C/D: col=lane&15, row=(lane>>4)*4+reg
  const long ocol = bcol + wc * 64 + l16;
#pragma unroll
  for (int m = 0; m < 4; ++m) {
#pragma unroll
    for (int reg = 0; reg < 4; ++reg) {
      const long r = orow + m * 16 + reg;
#pragma unroll
      for (int n = 0; n < 4; ++n) {
        const size_t idx = (size_t)r * N + ocol + n * 16;
        const float v = acc[m][n][reg];
        if constexpr (EPI == 0) {
          Cb[idx] = __float2bfloat16(v);
        } else if constexpr (EPI == 1) {
          Cf[idx] = addf[idx] + v;
        } else if constexpr (EPI == 2) {
          float t = v > 0.f ? v : 0.f;
          Cb[idx] = __float2bfloat16(t * t);
        } else if constexpr (EPI == 3) {
          Cb[idx] = __float2bfloat16(1.f / (1.f + __expf(-v)));
        } else if constexpr (EPI == 4) {
          Cf[idx] = v;
        } else if constexpr (EPI == 5) {
          Cf[idx] += v;
        } else {
          Cf[idx] = addf[idx] + __bfloat162float(mulb[idx]) * (Cf[idx] + v);
        }
      }
    }
  }
}

extern "C" void kernel_launch(void* const* d_in, const int* in_sizes, int n_in,
                              void* d_out, int out_size, void* d_ws, size_t ws_size,
                              hipStream_t stream) {
  const float* x    = (const float*)d_in[0];
  const float* ln1g = (const float*)d_in[1];
  const float* ln1b = (const float*)d_in[2];
  const float* Wk   = (const float*)d_in[3];
  const float* Wv   = (const float*)d_in[4];
  const float* Wr   = (const float*)d_in[5];
  const float* Wo   = (const float*)d_in[6];
  const float* td   = (const float*)d_in[7];
  const float* tf   = (const float*)d_in[8];
  const float* mk   = (const float*)d_in[9];
  const float* mv   = (const float*)d_in[10];
  const float* mr   = (const float*)d_in[11];
  const float* ln2g = (const float*)d_in[12];
  const float* ln2b = (const float*)d_in[13];
  const float* Wfk  = (const float*)d_in[14];
  const float* Wfv  = (const float*)d_in[15];
  const float* Wfr  = (const float*)d_in[16];

  char* ws = (char*)d_ws;
  const size_t MB = 1ull << 20;
  // [0,26) weights bf16 (transposed), [26,27) LN stats; peak ws use = 220 MiB
  bf16_t* WkT  = (bf16_t*)(ws + 0 * MB);
  bf16_t* WvT  = (bf16_t*)(ws + 2 * MB);
  bf16_t* WrT  = (bf16_t*)(ws + 4 * MB);
  bf16_t* WoT  = (bf16_t*)(ws + 6 * MB);
  bf16_t* WfkT = (bf16_t*)(ws + 8 * MB);    // [4096][1024]
  bf16_t* WfvT = (bf16_t*)(ws + 16 * MB);   // [1024][4096]
  bf16_t* WfrT = (bf16_t*)(ws + 24 * MB);
  float* mean1 = (float*)(ws + 26 * MB);
  float* rstd1 = (float*)(ws + 26 * MB + 65536);
  float* mean2 = (float*)(ws + 26 * MB + 131072);
  float* rstd2 = (float*)(ws + 26 * MB + 196608);
  bf16_t* xk   = (bf16_t*)(ws + 28 * MB);   // later: rwkv, then kk-chunk
  bf16_t* xv   = (bf16_t*)(ws + 60 * MB);   // later: wkv seg/carry scratch, then ymix
  bf16_t* xr   = (bf16_t*)(ws + 92 * MB);   // later: ynb
  bf16_t* kbuf = (bf16_t*)(ws + 124 * MB);  // later: x1 (f32, 124..188)
  bf16_t* vbuf = (bf16_t*)(ws + 156 * MB);
  bf16_t* rbuf = (bf16_t*)(ws + 188 * MB);  // later: rr
  bf16_t* rwkv = (bf16_t*)(ws + 28 * MB);
  float*  segA = (float*)(ws + 60 * MB);    // 8*32*1024*4 = 1 MB each
  float*  segB = (float*)(ws + 61 * MB);
  float*  carA = (float*)(ws + 62 * MB);
  float*  carB = (float*)(ws + 63 * MB);
  float*  x1   = (float*)(ws + 124 * MB);
  bf16_t* ymix = (bf16_t*)(ws + 60 * MB);
  bf16_t* ynb  = (bf16_t*)(ws + 92 * MB);
  bf16_t* rr   = (bf16_t*)(ws + 188 * MB);
  bf16_t* kkc  = (bf16_t*)(ws + 28 * MB);
  float*  out  = (float*)d_out;

  dim3 blk(256);
  // weights -> bf16 B^T
  k_transpose_cast<<<dim3(32, 32), blk, 0, stream>>>(Wk, WkT, 1024, 1024);
  k_transpose_cast<<<dim3(32, 32), blk, 0, stream>>>(Wv, WvT, 1024, 1024);
  k_transpose_cast<<<dim3(32, 32), blk, 0, stream>>>(Wr, WrT, 1024, 1024);
  k_transpose_cast<<<dim3(32, 32), blk, 0, stream>>>(Wo, WoT, 1024, 1024);
  k_transpose_cast<<<dim3(128, 32), blk, 0, stream>>>(Wfk, WfkT, 1024, 4096);
  k_transpose_cast<<<dim3(32, 128), blk, 0, stream>>>(Wfv, WfvT, 4096, 1024);
  k_transpose_cast<<<dim3(32, 32), blk, 0, stream>>>(Wfr, WfrT, 1024, 1024);

  // time mixing
  k_ln_stats<<<kM / 4, blk, 0, stream>>>(x, mean1, rstd1);
  k_ln_mix1<<<kM, blk, 0, stream>>>(x, mean1, rstd1, ln1g, ln1b, mk, mv, mr, xk, xv, xr);
  gemm128<0><<<dim3(8, 128), blk, 0, stream>>>(xk, 1024, WkT, 1024, 1024, 1024, nullptr, kbuf, nullptr, nullptr);
  gemm128<0><<<dim3(8, 128), blk, 0, stream>>>(xv, 1024, WvT, 1024, 1024, 1024, nullptr, vbuf, nullptr, nullptr);
  gemm128<0><<<dim3(8, 128), blk, 0, stream>>>(xr, 1024, WrT, 1024, 1024, 1024, nullptr, rbuf, nullptr, nullptr);
  // WKV segmented scan (seg/carry scratch lives in the dead xv region)
  k_wkv_seg<<<dim3(4, 8, kSeg), blk, 0, stream>>>((const unsigned short*)kbuf,
      (const unsigned short*)vbuf, td, tf, segA, segB);
  k_wkv_carry<<<dim3(4, 8), blk, 0, stream>>>(td, segA, segB, carA, carB);
  k_wkv_out<<<dim3(4, 8, kSeg), blk, 0, stream>>>((const unsigned short*)kbuf,
      (const unsigned short*)vbuf, (const unsigned short*)rbuf, td, tf, carA, carB,
      (unsigned short*)rwkv);
  gemm128<1><<<dim3(8, 128), blk, 0, stream>>>(rwkv, 1024, WoT, 1024, 1024, 1024, x1, nullptr, x, nullptr);

  // channel mixing
  k_ln_stats<<<kM / 4, blk, 0, stream>>>(x1, mean2, rstd2);
  k_ln_mix2<<<kM, blk, 0, stream>>>(x1, mean2, rstd2, ln2g, ln2b, ymix, ynb);
  gemm128<3><<<dim3(8, 128), blk, 0, stream>>>(ynb, 1024, WfrT, 1024, 1024, 1024, nullptr, rr, nullptr, nullptr);
  // hidden dim chunked by 1024: kkc = relu(ymix@Wfk[:,c])^2 ; out (+)= kkc@Wfv[c,:]
  for (int c = 0; c < 4; ++c) {
    gemm128<2><<<dim3(8, 128), blk, 0, stream>>>(ymix, 1024, WfkT + (size_t)c * 1024 * 1024, 1024,
                                                 1024, 1024, nullptr, kkc, nullptr, nullptr);
    if (c == 0)
      gemm128<4><<<dim3(8, 128), blk, 0, stream>>>(kkc, 1024, WfvT + (size_t)c * 1024, 4096,
                                                   1024, 1024, out, nullptr, nullptr, nullptr);
    else if (c < 3)
      gemm128<5><<<dim3(8, 128), blk, 0, stream>>>(kkc, 1024, WfvT + (size_t)c * 1024, 4096,
                                                   1024, 1024, out, nullptr, nullptr, nullptr);
    else
      gemm128<6><<<dim3(8, 128), blk, 0, stream>>>(kkc, 1024, WfvT + (size_t)c * 1024, 4096,
                                                   1024, 1024, out, nullptr, x1, rr);
  }
}